// Round 1
// 1279.850 us; speedup vs baseline: 1.3016x; 1.3016x over previous
//
#include <hip/hip_runtime.h>
#include <stdint.h>

#define Hdim 4096
#define Bdim 4096
#define BHn  (Bdim * (long)Hdim)

typedef __attribute__((ext_vector_type(8))) short bf16x8;
typedef __attribute__((ext_vector_type(4))) short short4v;
typedef __attribute__((ext_vector_type(4))) float f32x4;

// fp32 -> bf16 (round-to-nearest-even), header-version independent
__device__ inline short f2bf(float f) {
    uint32_t u = __builtin_bit_cast(uint32_t, f);
    u += 0x7fffu + ((u >> 16) & 1u);
    return (short)(u >> 16);
}

// ---------- W [K,N] fp32 row-major -> Wt [N,K] bf16 row-major ----------
__global__ __launch_bounds__(256) void transpose_convert(
    const float* __restrict__ W, short* __restrict__ Wt) {
    __shared__ float tile[32][33];
    const int tx = threadIdx.x, ty = threadIdx.y;
    const int n0 = blockIdx.x * 32, k0 = blockIdx.y * 32;
#pragma unroll
    for (int j = 0; j < 32; j += 8)
        tile[ty + j][tx] = W[(long)(k0 + ty + j) * Hdim + n0 + tx];
    __syncthreads();
#pragma unroll
    for (int j = 0; j < 32; j += 8)
        Wt[(long)(n0 + ty + j) * Hdim + k0 + tx] = f2bf(tile[tx][ty + j]);
}

// ---------- token-shift mix: xk/xv/xr (bf16) + x copy ----------
__global__ __launch_bounds__(256) void mix_kernel(
    const float* __restrict__ x, const float* __restrict__ sx,
    const float* __restrict__ km, const float* __restrict__ vm, const float* __restrict__ rm,
    short* __restrict__ xk, short* __restrict__ xv, short* __restrict__ xr,
    float* __restrict__ xcopy) {
    const long i = ((long)blockIdx.x * blockDim.x + threadIdx.x) * 4;
    const int h = (int)(i & (Hdim - 1));
    float4 x4 = *(const float4*)(x + i);
    float4 s4 = *(const float4*)(sx + i);
    float4 k4 = *(const float4*)(km + h);
    float4 v4 = *(const float4*)(vm + h);
    float4 r4 = *(const float4*)(rm + h);
    *(float4*)(xcopy + i) = x4;
    const float* xp = (const float*)&x4;
    const float* sp = (const float*)&s4;
    const float* kp = (const float*)&k4;
    const float* vp = (const float*)&v4;
    const float* rp = (const float*)&r4;
    short4v ok, ov, orr;
#pragma unroll
    for (int e = 0; e < 4; ++e) {
        float d = xp[e] - sp[e];
        ok[e]  = f2bf(fmaf(kp[e], d, sp[e]));
        ov[e]  = f2bf(fmaf(vp[e], d, sp[e]));
        orr[e] = f2bf(fmaf(rp[e], d, sp[e]));
    }
    *(short4v*)(xk + i) = ok;
    *(short4v*)(xv + i) = ov;
    *(short4v*)(xr + i) = orr;
}

// ---------- WKV elementwise (in-place over k/v/rpre -> aa/bb/p2) ----------
__global__ __launch_bounds__(256) void wkv_kernel(
    float* __restrict__ kbuf,   // in: k,    out: aa
    float* __restrict__ vbuf,   // in: v,    out: bb
    float* __restrict__ rbuf,   // in: rpre, out: p2
    const float* __restrict__ sa, const float* __restrict__ sb, const float* __restrict__ spv,
    const float* __restrict__ td, const float* __restrict__ tf,
    short* __restrict__ rwkv) {
    const long i = ((long)blockIdx.x * blockDim.x + threadIdx.x) * 4;
    const int h = (int)(i & (Hdim - 1));
    float4 k4 = *(const float4*)(kbuf + i);
    float4 v4 = *(const float4*)(vbuf + i);
    float4 r4 = *(const float4*)(rbuf + i);
    float4 a4 = *(const float4*)(sa + i);
    float4 b4 = *(const float4*)(sb + i);
    float4 p4 = *(const float4*)(spv + i);
    float4 t4 = *(const float4*)(td + h);
    float4 f4 = *(const float4*)(tf + h);
    const float* kp = (const float*)&k4; const float* vp = (const float*)&v4;
    const float* rp = (const float*)&r4; const float* ap = (const float*)&a4;
    const float* bp = (const float*)&b4; const float* pp = (const float*)&p4;
    const float* tp = (const float*)&t4; const float* fp = (const float*)&f4;
    float4 aa4, bb4, p24; short4v rw;
    float* aao = (float*)&aa4; float* bbo = (float*)&bb4; float* p2o = (float*)&p24;
#pragma unroll
    for (int e = 0; e < 4; ++e) {
        float k = kp[e], v = vp[e], A = ap[e], Bb = bp[e], P = pp[e];
        float r = 1.f / (1.f + __expf(-rp[e]));
        float w = k + fp[e];
        float p = fmaxf(P, w);
        float e1 = __expf(P - p), e2 = __expf(w - p);
        float wkv = (e1 * A + e2 * v) / (e1 * Bb + e2);
        float w2 = P + tp[e];
        float pq = fmaxf(w2, k);
        float E1 = __expf(w2 - pq), E2 = __expf(k - pq);
        aao[e] = E1 * A + E2 * v;
        bbo[e] = E1 * Bb + E2;
        p2o[e] = pq;
        rw[e] = f2bf(r * wkv);
    }
    *(float4*)(kbuf + i) = aa4;
    *(float4*)(vbuf + i) = bb4;
    *(float4*)(rbuf + i) = p24;
    *(short4v*)(rwkv + i) = rw;
}

// ================= GEMM: 256x256 tile, BK=64, 8 waves, 8-phase pipeline ======
// C[M,N] fp32 = A[M,K] bf16 @ Bt[N,K]^T bf16
// LDS (shorts): A(slot,kh) at (slot*2+kh)*8192 ; B(slot,kh) at 32768 + same.
// Each half = 256 rows x 32 k. Swizzle: 16B-group g' = g ^ ((row>>1)&3),
// applied on the global SOURCE (linear LDS dest for global_load_lds) and on
// the ds_read address — both sides, same involution (rule #21).

#define MFMA16 __builtin_amdgcn_mfma_f32_16x16x32_bf16

__device__ __forceinline__ void stage_half(
    const short* __restrict__ G, const int ldk,
    const int row_base, const int kstart,
    short* lhalf, const int tid) {
    const int q = tid >> 2;                        // row within 128-row chunk
    const int g = (tid & 3) ^ ((tid >> 3) & 3);    // pre-swizzled source group
    const short* src0 = G + (long)(row_base + q) * ldk + kstart + g * 8;
    short* dst0 = lhalf + (tid >> 6) * 512;        // wave-uniform linear dest
    __builtin_amdgcn_global_load_lds(
        (const __attribute__((address_space(1))) void*)src0,
        (__attribute__((address_space(3))) void*)dst0, 16, 0, 0);
    __builtin_amdgcn_global_load_lds(
        (const __attribute__((address_space(1))) void*)(src0 + (long)128 * ldk),
        (__attribute__((address_space(3))) void*)(dst0 + 4096), 16, 0, 0);
}

template <int SLOT>
__device__ __forceinline__ void tile_body(
    const short* __restrict__ Ag, const short* __restrict__ Btg,
    short* lds, const int tt, const int NT, const int K,
    const int m_blk, const int n_blk, const int tid,
    const int aoff, const int boff, f32x4 (&acc)[8][4]) {
    const short* As0 = lds + SLOT * 16384;
    const short* As1 = As0 + 8192;
    const short* Bs0 = lds + 32768 + SLOT * 16384;
    const short* Bs1 = Bs0 + 8192;

    bf16x8 af[8], b0, b1;

    // ---- P0: ks=0, j={0,1}; stage B-kh1(tt+1) ----
#pragma unroll
    for (int i = 0; i < 8; ++i) af[i] = *(const bf16x8*)(As0 + aoff + i * 512);
    b0 = *(const bf16x8*)(Bs0 + boff);
    b1 = *(const bf16x8*)(Bs0 + boff + 512);
    if (tt + 1 < NT)
        stage_half(Btg, K, n_blk, (tt + 1) * 64 + 32,
                   lds + 32768 + (1 - SLOT) * 16384 + 8192, tid);
    __builtin_amdgcn_s_barrier();
    asm volatile("s_waitcnt lgkmcnt(0)" ::: "memory");
    __builtin_amdgcn_sched_barrier(0);
    __builtin_amdgcn_s_setprio(1);
#pragma unroll
    for (int i = 0; i < 8; ++i) {
        acc[i][0] = MFMA16(af[i], b0, acc[i][0], 0, 0, 0);
        acc[i][1] = MFMA16(af[i], b1, acc[i][1], 0, 0, 0);
    }
    __builtin_amdgcn_s_setprio(0);
    __builtin_amdgcn_s_barrier();

    // ---- P1: ks=0, j={2,3}; stage A-kh0(tt+2) ----
    b0 = *(const bf16x8*)(Bs0 + boff + 1024);
    b1 = *(const bf16x8*)(Bs0 + boff + 1536);
    if (tt + 2 < NT)
        stage_half(Ag, K, m_blk, (tt + 2) * 64, lds + SLOT * 16384, tid);
    __builtin_amdgcn_s_barrier();
    asm volatile("s_waitcnt lgkmcnt(0)" ::: "memory");
    __builtin_amdgcn_sched_barrier(0);
    __builtin_amdgcn_s_setprio(1);
#pragma unroll
    for (int i = 0; i < 8; ++i) {
        acc[i][2] = MFMA16(af[i], b0, acc[i][2], 0, 0, 0);
        acc[i][3] = MFMA16(af[i], b1, acc[i][3], 0, 0, 0);
    }
    __builtin_amdgcn_s_setprio(0);
    __builtin_amdgcn_s_barrier();

    // ---- P2: ks=1, j={0,1}; stage B-kh0(tt+2) ----
#pragma unroll
    for (int i = 0; i < 8; ++i) af[i] = *(const bf16x8*)(As1 + aoff + i * 512);
    b0 = *(const bf16x8*)(Bs1 + boff);
    b1 = *(const bf16x8*)(Bs1 + boff + 512);
    if (tt + 2 < NT)
        stage_half(Btg, K, n_blk, (tt + 2) * 64, lds + 32768 + SLOT * 16384, tid);
    __builtin_amdgcn_s_barrier();
    asm volatile("s_waitcnt lgkmcnt(0)" ::: "memory");
    __builtin_amdgcn_sched_barrier(0);
    __builtin_amdgcn_s_setprio(1);
#pragma unroll
    for (int i = 0; i < 8; ++i) {
        acc[i][0] = MFMA16(af[i], b0, acc[i][0], 0, 0, 0);
        acc[i][1] = MFMA16(af[i], b1, acc[i][1], 0, 0, 0);
    }
    __builtin_amdgcn_s_setprio(0);
    __builtin_amdgcn_s_barrier();

    // ---- P3: ks=1, j={2,3}; stage A-kh1(tt+2); boundary vmcnt ----
    b0 = *(const bf16x8*)(Bs1 + boff + 1024);
    b1 = *(const bf16x8*)(Bs1 + boff + 1536);
    if (tt + 2 < NT)
        stage_half(Ag, K, m_blk, (tt + 2) * 64 + 32, lds + SLOT * 16384 + 8192, tid);
    __builtin_amdgcn_s_barrier();
    asm volatile("s_waitcnt lgkmcnt(0)" ::: "memory");
    __builtin_amdgcn_sched_barrier(0);
    __builtin_amdgcn_s_setprio(1);
#pragma unroll
    for (int i = 0; i < 8; ++i) {
        acc[i][2] = MFMA16(af[i], b0, acc[i][2], 0, 0, 0);
        acc[i][3] = MFMA16(af[i], b1, acc[i][3], 0, 0, 0);
    }
    __builtin_amdgcn_s_setprio(0);
    // counted boundary wait: 3 half-tiles (6 loads) stay in flight
    if (tt + 2 < NT) asm volatile("s_waitcnt vmcnt(6)" ::: "memory");
    else             asm volatile("s_waitcnt vmcnt(0)" ::: "memory");
    __builtin_amdgcn_s_barrier();
}

__global__ __launch_bounds__(512, 2) void gemm_bt8(
    const short* __restrict__ A, const short* __restrict__ Bt,
    float* __restrict__ C, int M, int N, int K) {
    __shared__ __align__(16) short lds[65536];   // 128 KiB

    const int tid  = threadIdx.x;
    const int wid  = tid >> 6;
    const int lane = tid & 63;

    // XCD-aware bijective swizzle (nwg = 256, divisible by 8)
    const int nwg = gridDim.x;
    const int bid = blockIdx.x;
    const int swz = (bid & 7) * (nwg >> 3) + (bid >> 3);
    const int nbx = N >> 8;                      // N / 256
    const int m_blk = (swz / nbx) * 256;
    const int n_blk = (swz % nbx) * 256;

    const int wm = (wid >> 2) * 128;             // 0 / 128
    const int wn = (wid & 3) * 64;               // 0 / 64 / 128 / 192

    const int l15 = lane & 15;
    const int gsw = (lane >> 4) ^ ((l15 >> 1) & 3);   // swizzled 16B group
    const int aoff = (wm + l15) * 32 + gsw * 8;       // element offset in a half
    const int boff = (wn + l15) * 32 + gsw * 8;

    f32x4 acc[8][4] = {};

    const int NT = K >> 6;                       // K / 64

    // ---- prologue: prime 7 half-tiles (tile0 full + tile1 A0,B0,A1) ----
    stage_half(A,  K, m_blk, 0,  lds,                 tid);   // A0(0)
    stage_half(Bt, K, n_blk, 0,  lds + 32768,         tid);   // B0(0)
    stage_half(A,  K, m_blk, 32, lds + 8192,          tid);   // A1(0)
    stage_half(Bt, K, n_blk, 32, lds + 32768 + 8192,  tid);   // B1(0)
    stage_half(A,  K, m_blk, 64, lds + 16384,         tid);   // A0(1)
    stage_half(Bt, K, n_blk, 64, lds + 32768 + 16384, tid);   // B0(1)
    stage_half(A,  K, m_blk, 96, lds + 16384 + 8192,  tid);   // A1(1)
    asm volatile("s_waitcnt vmcnt(6)" ::: "memory");          // tile0 complete
    __builtin_amdgcn_s_barrier();

    for (int t = 0; t < NT; t += 2) {
        tile_body<0>(A, Bt, lds, t,     NT, K, m_blk, n_blk, tid, aoff, boff, acc);
        tile_body<1>(A, Bt, lds, t + 1, NT, K, m_blk, n_blk, tid, aoff, boff, acc);
    }

    // epilogue: C/D layout col=lane&15, row=(lane>>4)*4+reg
    const int crow0 = m_blk + wm + (lane >> 4) * 4;
    const int ccol  = n_blk + wn + l15;
#pragma unroll
    for (int i = 0; i < 8; ++i)
#pragma unroll
        for (int j = 0; j < 4; ++j) {
            float* cp = C + (long)(crow0 + i * 16) * N + ccol + j * 16;
#pragma unroll
            for (int r = 0; r < 4; ++r)
                cp[(long)r * N] = acc[i][j][r];
        }
}

extern "C" void kernel_launch(void* const* d_in, const int* in_sizes, int n_in,
                              void* d_out, int out_size, void* d_ws, size_t ws_size,
                              hipStream_t stream) {
    const float* x  = (const float*)d_in[0];
    const float* sx = (const float*)d_in[1];
    const float* sa = (const float*)d_in[2];
    const float* sb = (const float*)d_in[3];
    const float* sp = (const float*)d_in[4];
    const float* td = (const float*)d_in[5];
    const float* tf = (const float*)d_in[6];
    const float* km = (const float*)d_in[7];
    const float* vm = (const float*)d_in[8];
    const float* rm = (const float*)d_in[9];
    const float* Wk = (const float*)d_in[10];
    const float* Wv = (const float*)d_in[11];
    const float* Wr = (const float*)d_in[12];
    const float* Wo = (const float*)d_in[13];

    float* out   = (float*)d_out;          // slot 0: out
    float* xcopy = out + BHn;              // slot 1: x
    float* kbuf  = out + 2 * BHn;          // slot 2: k -> aa
    float* vbuf  = out + 3 * BHn;          // slot 3: v -> bb
    float* rbuf  = out + 4 * BHn;          // slot 4: rpre -> p2

    short* wsW  = (short*)d_ws;            // H*H bf16 weight buffer (reused 4x)
    short* xk   = wsW + (long)Hdim * Hdim;
    short* xv   = xk + BHn;
    short* xr   = xv + BHn;
    short* rwkv = xk;                      // xk dead after first GEMM

    dim3 tb(32, 8), tg(Hdim / 32, Hdim / 32);
    dim3 gg((Hdim / 256) * (Bdim / 256));  // 256 blocks, 1 per CU
    const int ew_blocks = (int)(BHn / 1024);   // 4 elems/thread, 256 thr/block

    mix_kernel<<<ew_blocks, 256, 0, stream>>>(x, sx, km, vm, rm, xk, xv, xr, xcopy);

    transpose_convert<<<tg, tb, 0, stream>>>(Wk, wsW);
    gemm_bt8<<<gg, 512, 0, stream>>>(xk, wsW, kbuf, Bdim, Hdim, Hdim);
    transpose_convert<<<tg, tb, 0, stream>>>(Wv, wsW);
    gemm_bt8<<<gg, 512, 0, stream>>>(xv, wsW, vbuf, Bdim, Hdim, Hdim);
    transpose_convert<<<tg, tb, 0, stream>>>(Wr, wsW);
    gemm_bt8<<<gg, 512, 0, stream>>>(xr, wsW, rbuf, Bdim, Hdim, Hdim);

    wkv_kernel<<<ew_blocks, 256, 0, stream>>>(kbuf, vbuf, rbuf, sa, sb, sp, td, tf, rwkv);

    transpose_convert<<<tg, tb, 0, stream>>>(Wo, wsW);
    gemm_bt8<<<gg, 512, 0, stream>>>(rwkv, wsW, out, Bdim, Hdim, Hdim);
}

// Round 2
// 1272.887 us; speedup vs baseline: 1.3088x; 1.0055x over previous
//
#include <hip/hip_runtime.h>
#include <stdint.h>

#define Hdim 4096
#define Bdim 4096
#define BHn  (Bdim * (long)Hdim)

typedef __attribute__((ext_vector_type(8))) short bf16x8;
typedef __attribute__((ext_vector_type(4))) short short4v;
typedef __attribute__((ext_vector_type(4))) float f32x4;

// fp32 -> bf16 (round-to-nearest-even), header-version independent
__device__ inline short f2bf(float f) {
    uint32_t u = __builtin_bit_cast(uint32_t, f);
    u += 0x7fffu + ((u >> 16) & 1u);
    return (short)(u >> 16);
}

// ---------- W [K,N] fp32 row-major -> Wt [N,K] bf16 row-major ----------
// 64x64 tile, 256 threads. Coalesced float4 loads, 16B bf16x8 stores.
// LDS pad 65: store-phase read banks = ((l&7)*8 + e + (l>>3)) mod 32 -> 2-way (free).
__global__ __launch_bounds__(256) void transpose_convert(
    const float* __restrict__ W, short* __restrict__ Wt) {
    __shared__ float tile[64][65];
    const int t = threadIdx.x;
    const int n0 = blockIdx.x * 64, k0 = blockIdx.y * 64;
    {
        const int r = t >> 4;            // k-local row 0..15 per pass
        const int c = (t & 15) * 4;      // n-local col
#pragma unroll
        for (int j = 0; j < 64; j += 16) {
            float4 v = *(const float4*)(W + (long)(k0 + r + j) * Hdim + n0 + c);
            tile[r + j][c]     = v.x;
            tile[r + j][c + 1] = v.y;
            tile[r + j][c + 2] = v.z;
            tile[r + j][c + 3] = v.w;
        }
    }
    __syncthreads();
    {
        const int rr = t >> 3;           // n-local row 0..31 per pass
        const int cc = (t & 7) * 8;      // k-local col
#pragma unroll
        for (int j = 0; j < 64; j += 32) {
            bf16x8 o;
#pragma unroll
            for (int e = 0; e < 8; ++e)
                o[e] = f2bf(tile[cc + e][rr + j]);
            *(bf16x8*)(Wt + (long)(n0 + rr + j) * Hdim + k0 + cc) = o;
        }
    }
}

// ---------- token-shift mix: xk/xv/xr (bf16, 16B stores) + x copy ----------
__global__ __launch_bounds__(256) void mix_kernel(
    const float* __restrict__ x, const float* __restrict__ sx,
    const float* __restrict__ km, const float* __restrict__ vm, const float* __restrict__ rm,
    short* __restrict__ xk, short* __restrict__ xv, short* __restrict__ xr,
    float* __restrict__ xcopy) {
    const long i = ((long)blockIdx.x * blockDim.x + threadIdx.x) * 8;
    const int h = (int)(i & (Hdim - 1));
    float4 x0 = *(const float4*)(x + i),  x1 = *(const float4*)(x + i + 4);
    float4 s0 = *(const float4*)(sx + i), s1 = *(const float4*)(sx + i + 4);
    float4 k0 = *(const float4*)(km + h), k1 = *(const float4*)(km + h + 4);
    float4 v0 = *(const float4*)(vm + h), v1 = *(const float4*)(vm + h + 4);
    float4 r0 = *(const float4*)(rm + h), r1 = *(const float4*)(rm + h + 4);
    *(float4*)(xcopy + i)     = x0;
    *(float4*)(xcopy + i + 4) = x1;
    const float* xp0 = (const float*)&x0; const float* xp1 = (const float*)&x1;
    const float* sp0 = (const float*)&s0; const float* sp1 = (const float*)&s1;
    const float* kp0 = (const float*)&k0; const float* kp1 = (const float*)&k1;
    const float* vp0 = (const float*)&v0; const float* vp1 = (const float*)&v1;
    const float* rp0 = (const float*)&r0; const float* rp1 = (const float*)&r1;
    bf16x8 ok, ov, orr;
#pragma unroll
    for (int e = 0; e < 4; ++e) {
        float d = xp0[e] - sp0[e];
        ok[e]  = f2bf(fmaf(kp0[e], d, sp0[e]));
        ov[e]  = f2bf(fmaf(vp0[e], d, sp0[e]));
        orr[e] = f2bf(fmaf(rp0[e], d, sp0[e]));
    }
#pragma unroll
    for (int e = 0; e < 4; ++e) {
        float d = xp1[e] - sp1[e];
        ok[e + 4]  = f2bf(fmaf(kp1[e], d, sp1[e]));
        ov[e + 4]  = f2bf(fmaf(vp1[e], d, sp1[e]));
        orr[e + 4] = f2bf(fmaf(rp1[e], d, sp1[e]));
    }
    *(bf16x8*)(xk + i) = ok;
    *(bf16x8*)(xv + i) = ov;
    *(bf16x8*)(xr + i) = orr;
}

// ================= GEMM: 256x256 tile, BK=64, 8 waves, 8-phase pipeline ======
// C[M,N] fp32 = A[M,K] bf16 @ Bt[N,K]^T bf16
// FUSE=1: epilogue consumes acc as rpre and performs the WKV update in-place
// (kb: k->aa, vb: v->bb, C: p2, rwkv: bf16 r*wkv), eliminating wkv_kernel.

#define MFMA16 __builtin_amdgcn_mfma_f32_16x16x32_bf16

__device__ __forceinline__ void stage_half(
    const short* __restrict__ G, const int ldk,
    const int row_base, const int kstart,
    short* lhalf, const int tid) {
    const int q = tid >> 2;                        // row within 128-row chunk
    const int g = (tid & 3) ^ ((tid >> 3) & 3);    // pre-swizzled source group
    const short* src0 = G + (long)(row_base + q) * ldk + kstart + g * 8;
    short* dst0 = lhalf + (tid >> 6) * 512;        // wave-uniform linear dest
    __builtin_amdgcn_global_load_lds(
        (const __attribute__((address_space(1))) void*)src0,
        (__attribute__((address_space(3))) void*)dst0, 16, 0, 0);
    __builtin_amdgcn_global_load_lds(
        (const __attribute__((address_space(1))) void*)(src0 + (long)128 * ldk),
        (__attribute__((address_space(3))) void*)(dst0 + 4096), 16, 0, 0);
}

template <int SLOT>
__device__ __forceinline__ void tile_body(
    const short* __restrict__ Ag, const short* __restrict__ Btg,
    short* lds, const int tt, const int NT, const int K,
    const int m_blk, const int n_blk, const int tid,
    const int aoff, const int boff, f32x4 (&acc)[8][4]) {
    const short* As0 = lds + SLOT * 16384;
    const short* As1 = As0 + 8192;
    const short* Bs0 = lds + 32768 + SLOT * 16384;
    const short* Bs1 = Bs0 + 8192;

    bf16x8 af[8], b0, b1;

    // ---- P0: ks=0, j={0,1}; stage B-kh1(tt+1) ----
#pragma unroll
    for (int i = 0; i < 8; ++i) af[i] = *(const bf16x8*)(As0 + aoff + i * 512);
    b0 = *(const bf16x8*)(Bs0 + boff);
    b1 = *(const bf16x8*)(Bs0 + boff + 512);
    if (tt + 1 < NT)
        stage_half(Btg, K, n_blk, (tt + 1) * 64 + 32,
                   lds + 32768 + (1 - SLOT) * 16384 + 8192, tid);
    __builtin_amdgcn_s_barrier();
    asm volatile("s_waitcnt lgkmcnt(0)" ::: "memory");
    __builtin_amdgcn_sched_barrier(0);
    __builtin_amdgcn_s_setprio(1);
#pragma unroll
    for (int i = 0; i < 8; ++i) {
        acc[i][0] = MFMA16(af[i], b0, acc[i][0], 0, 0, 0);
        acc[i][1] = MFMA16(af[i], b1, acc[i][1], 0, 0, 0);
    }
    __builtin_amdgcn_s_setprio(0);
    __builtin_amdgcn_s_barrier();

    // ---- P1: ks=0, j={2,3}; stage A-kh0(tt+2) ----
    b0 = *(const bf16x8*)(Bs0 + boff + 1024);
    b1 = *(const bf16x8*)(Bs0 + boff + 1536);
    if (tt + 2 < NT)
        stage_half(Ag, K, m_blk, (tt + 2) * 64, lds + SLOT * 16384, tid);
    __builtin_amdgcn_s_barrier();
    asm volatile("s_waitcnt lgkmcnt(0)" ::: "memory");
    __builtin_amdgcn_sched_barrier(0);
    __builtin_amdgcn_s_setprio(1);
#pragma unroll
    for (int i = 0; i < 8; ++i) {
        acc[i][2] = MFMA16(af[i], b0, acc[i][2], 0, 0, 0);
        acc[i][3] = MFMA16(af[i], b1, acc[i][3], 0, 0, 0);
    }
    __builtin_amdgcn_s_setprio(0);
    __builtin_amdgcn_s_barrier();

    // ---- P2: ks=1, j={0,1}; stage B-kh0(tt+2) ----
#pragma unroll
    for (int i = 0; i < 8; ++i) af[i] = *(const bf16x8*)(As1 + aoff + i * 512);
    b0 = *(const bf16x8*)(Bs1 + boff);
    b1 = *(const bf16x8*)(Bs1 + boff + 512);
    if (tt + 2 < NT)
        stage_half(Btg, K, n_blk, (tt + 2) * 64, lds + 32768 + SLOT * 16384, tid);
    __builtin_amdgcn_s_barrier();
    asm volatile("s_waitcnt lgkmcnt(0)" ::: "memory");
    __builtin_amdgcn_sched_barrier(0);
    __builtin_amdgcn_s_setprio(1);
#pragma unroll
    for (int i = 0; i < 8; ++i) {
        acc[i][0] = MFMA16(af[i], b0, acc[i][0], 0, 0, 0);
        acc[i][1] = MFMA16(af[i], b1, acc[i][1], 0, 0, 0);
    }
    __builtin_amdgcn_s_setprio(0);
    __builtin_amdgcn_s_barrier();

    // ---- P3: ks=1, j={2,3}; stage A-kh1(tt+2); boundary vmcnt ----
    b0 = *(const bf16x8*)(Bs1 + boff + 1024);
    b1 = *(const bf16x8*)(Bs1 + boff + 1536);
    if (tt + 2 < NT)
        stage_half(Ag, K, m_blk, (tt + 2) * 64 + 32, lds + SLOT * 16384 + 8192, tid);
    __builtin_amdgcn_s_barrier();
    asm volatile("s_waitcnt lgkmcnt(0)" ::: "memory");
    __builtin_amdgcn_sched_barrier(0);
    __builtin_amdgcn_s_setprio(1);
#pragma unroll
    for (int i = 0; i < 8; ++i) {
        acc[i][2] = MFMA16(af[i], b0, acc[i][2], 0, 0, 0);
        acc[i][3] = MFMA16(af[i], b1, acc[i][3], 0, 0, 0);
    }
    __builtin_amdgcn_s_setprio(0);
    // counted boundary wait: 3 half-tiles (6 loads) stay in flight
    if (tt + 2 < NT) asm volatile("s_waitcnt vmcnt(6)" ::: "memory");
    else             asm volatile("s_waitcnt vmcnt(0)" ::: "memory");
    __builtin_amdgcn_s_barrier();
}

template <int FUSE>
__global__ __launch_bounds__(512, 2) void gemm_bt8(
    const short* __restrict__ A, const short* __restrict__ Bt,
    float* __restrict__ C, int M, int N, int K,
    float* __restrict__ kb, float* __restrict__ vb,
    const float* __restrict__ sa, const float* __restrict__ sb,
    const float* __restrict__ sp,
    const float* __restrict__ td, const float* __restrict__ tf,
    short* __restrict__ rwkv) {
    __shared__ __align__(16) short lds[65536];   // 128 KiB

    const int tid  = threadIdx.x;
    const int wid  = tid >> 6;
    const int lane = tid & 63;

    // XCD-aware bijective swizzle (nwg = 256, divisible by 8)
    const int nwg = gridDim.x;
    const int bid = blockIdx.x;
    const int swz = (bid & 7) * (nwg >> 3) + (bid >> 3);
    const int nbx = N >> 8;                      // N / 256
    const int m_blk = (swz / nbx) * 256;
    const int n_blk = (swz % nbx) * 256;

    const int wm = (wid >> 2) * 128;             // 0 / 128
    const int wn = (wid & 3) * 64;               // 0 / 64 / 128 / 192

    const int l15 = lane & 15;
    const int gsw = (lane >> 4) ^ ((l15 >> 1) & 3);   // swizzled 16B group
    const int aoff = (wm + l15) * 32 + gsw * 8;       // element offset in a half
    const int boff = (wn + l15) * 32 + gsw * 8;

    f32x4 acc[8][4] = {};

    const int NT = K >> 6;                       // K / 64

    // ---- prologue: prime 7 half-tiles (tile0 full + tile1 A0,B0,A1) ----
    stage_half(A,  K, m_blk, 0,  lds,                 tid);   // A0(0)
    stage_half(Bt, K, n_blk, 0,  lds + 32768,         tid);   // B0(0)
    stage_half(A,  K, m_blk, 32, lds + 8192,          tid);   // A1(0)
    stage_half(Bt, K, n_blk, 32, lds + 32768 + 8192,  tid);   // B1(0)
    stage_half(A,  K, m_blk, 64, lds + 16384,         tid);   // A0(1)
    stage_half(Bt, K, n_blk, 64, lds + 32768 + 16384, tid);   // B0(1)
    stage_half(A,  K, m_blk, 96, lds + 16384 + 8192,  tid);   // A1(1)
    asm volatile("s_waitcnt vmcnt(6)" ::: "memory");          // tile0 complete
    __builtin_amdgcn_s_barrier();

    for (int t = 0; t < NT; t += 2) {
        tile_body<0>(A, Bt, lds, t,     NT, K, m_blk, n_blk, tid, aoff, boff, acc);
        tile_body<1>(A, Bt, lds, t + 1, NT, K, m_blk, n_blk, tid, aoff, boff, acc);
    }

    // epilogue: C/D layout col=lane&15, row=(lane>>4)*4+reg
    const int crow0 = m_blk + wm + (lane >> 4) * 4;
    const int ccol  = n_blk + wn + l15;

    if constexpr (FUSE == 0) {
#pragma unroll
        for (int i = 0; i < 8; ++i)
#pragma unroll
            for (int j = 0; j < 4; ++j) {
                float* cp = C + (long)(crow0 + i * 16) * N + ccol + j * 16;
#pragma unroll
                for (int r = 0; r < 4; ++r)
                    cp[(long)r * N] = acc[i][j][r];
            }
    } else {
        // fused WKV: acc = rpre; in-place k->aa, v->bb; C gets p2; rwkv bf16
        float tdc[4], tfc[4];
#pragma unroll
        for (int j = 0; j < 4; ++j) {
            tdc[j] = td[ccol + j * 16];
            tfc[j] = tf[ccol + j * 16];
        }
#pragma unroll
        for (int i = 0; i < 8; ++i)
#pragma unroll
            for (int j = 0; j < 4; ++j) {
                const long base = (long)(crow0 + i * 16) * N + ccol + j * 16;
#pragma unroll
                for (int r = 0; r < 4; ++r) {
                    const long idx = base + (long)r * N;
                    float k  = kb[idx], v = vb[idx];
                    float Aa = sa[idx], Bb = sb[idx], P = sp[idx];
                    float rr = 1.f / (1.f + __expf(-acc[i][j][r]));
                    float w  = k + tfc[j];
                    float p  = fmaxf(P, w);
                    float e1 = __expf(P - p), e2 = __expf(w - p);
                    float wkv = (e1 * Aa + e2 * v) / (e1 * Bb + e2);
                    float w2 = P + tdc[j];
                    float pq = fmaxf(w2, k);
                    float E1 = __expf(w2 - pq), E2 = __expf(k - pq);
                    kb[idx]   = E1 * Aa + E2 * v;
                    vb[idx]   = E1 * Bb + E2;
                    C[idx]    = pq;
                    rwkv[idx] = f2bf(rr * wkv);
                }
            }
    }
}

extern "C" void kernel_launch(void* const* d_in, const int* in_sizes, int n_in,
                              void* d_out, int out_size, void* d_ws, size_t ws_size,
                              hipStream_t stream) {
    const float* x  = (const float*)d_in[0];
    const float* sx = (const float*)d_in[1];
    const float* sa = (const float*)d_in[2];
    const float* sb = (const float*)d_in[3];
    const float* sp = (const float*)d_in[4];
    const float* td = (const float*)d_in[5];
    const float* tf = (const float*)d_in[6];
    const float* km = (const float*)d_in[7];
    const float* vm = (const float*)d_in[8];
    const float* rm = (const float*)d_in[9];
    const float* Wk = (const float*)d_in[10];
    const float* Wv = (const float*)d_in[11];
    const float* Wr = (const float*)d_in[12];
    const float* Wo = (const float*)d_in[13];

    float* out   = (float*)d_out;          // slot 0: out
    float* xcopy = out + BHn;              // slot 1: x
    float* kbuf  = out + 2 * BHn;          // slot 2: k -> aa
    float* vbuf  = out + 3 * BHn;          // slot 3: v -> bb
    float* rbuf  = out + 4 * BHn;          // slot 4: p2

    short* wsW  = (short*)d_ws;            // H*H bf16 weight buffer (reused 4x)
    short* xk   = wsW + (long)Hdim * Hdim;
    short* xv   = xk + BHn;
    short* xr   = xv + BHn;
    short* rwkv = xk;                      // xk dead after first GEMM

    dim3 tg(Hdim / 64, Hdim / 64);
    dim3 gg((Hdim / 256) * (Bdim / 256));  // 256 blocks, 1 per CU
    const int ew_blocks = (int)(BHn / 2048);   // 8 elems/thread, 256 thr/block

    mix_kernel<<<ew_blocks, 256, 0, stream>>>(x, sx, km, vm, rm, xk, xv, xr, xcopy);

    transpose_convert<<<tg, 256, 0, stream>>>(Wk, wsW);
    gemm_bt8<0><<<gg, 512, 0, stream>>>(xk, wsW, kbuf, Bdim, Hdim, Hdim,
                                        nullptr, nullptr, nullptr, nullptr,
                                        nullptr, nullptr, nullptr, nullptr);
    transpose_convert<<<tg, 256, 0, stream>>>(Wv, wsW);
    gemm_bt8<0><<<gg, 512, 0, stream>>>(xv, wsW, vbuf, Bdim, Hdim, Hdim,
                                        nullptr, nullptr, nullptr, nullptr,
                                        nullptr, nullptr, nullptr, nullptr);
    transpose_convert<<<tg, 256, 0, stream>>>(Wr, wsW);
    // fused: computes rpre in-register, applies WKV, writes aa/bb/p2 + rwkv
    gemm_bt8<1><<<gg, 512, 0, stream>>>(xr, wsW, rbuf, Bdim, Hdim, Hdim,
                                        kbuf, vbuf, sa, sb, sp, td, tf, rwkv);
    transpose_convert<<<tg, 256, 0, stream>>>(Wo, wsW);
    gemm_bt8<0><<<gg, 512, 0, stream>>>(rwkv, wsW, out, Bdim, Hdim, Hdim,
                                        nullptr, nullptr, nullptr, nullptr,
                                        nullptr, nullptr, nullptr, nullptr);
}